// Round 16
// baseline (486.379 us; speedup 1.0000x reference)
//
#include <hip/hip_runtime.h>
#include <hip/hip_fp16.h>
#include <hip/hip_cooperative_groups.h>

namespace cg = cooperative_groups;

// CTC loss (blank=0, mean reduction, zero_infinity) for
// B=64, T=1024, K=512, L=100  ->  S = 2L+1 = 201 extended states.
//
// Round-16: SINGLE cooperative kernel overlapping the BW-bound softmax
// production with the latency-bound recursion.
//   grid = 256 blocks x 768 threads (1 block/CU, 12 waves).
//   T split into 8 segments of 128 rows. 4 stages: stage k produces
//   segments {k, 7-k} for all 64 batches (16384 rows/stage) via 2944
//   producer waves (blocks 0-63: waves 2-11; blocks 64-255: all 12),
//   each prefetching up to 6 rows deep (global row-striping -> full-chip
//   BW; per-CU streaming caps at ~24GB/s, which killed the R6 fusion).
//   After each stage: fence(release,agent) -> cg grid.sync() ->
//   fence(acquire,agent). R11 lesson: cg sync alone leaves stale
//   cross-XCD data; R10 lesson: the explicit agent fences DO give
//   correct visibility — here amortized to 4 barriers.
//   Consumers (blocks 0-63, waves 0=fwd rows 0..511 / 1=bwd rows
//   1023..512 lane-reversed) consume segment s-1 during stage s; tail
//   consumes the last segment after the final sync. Recursion math is
//   bit-identical to the verified R15 kernel (fp16 pair-packed ratios,
//   per-lane power-of-2 rescale every 8 steps with integer exponents +
//   bit-built split factors, wave_shr:1 DPP cross-lane, log2-domain
//   combine -> wave logsumexp, atomicAdd(out, loss/64)).

#define TT 1024
#define BB 64
#define KK 512
#define LL 100
#define NPRODW 2944           // producer waves: 64*10 + 192*12
#define RPS 16384             // rows per stage (64 batches * 256 rows)

static constexpr float L2E = 1.44269504088896340736f;
static constexpr float LN2 = 0.69314718055994530942f;

// lane i <- lane i-1, lane 0 <- 0  (DPP wave_shr:1, VALU pipe)
__device__ __forceinline__ float dpp_shr1_z(float x) {
  return __builtin_bit_cast(float,
      __builtin_amdgcn_update_dpp(0, __builtin_bit_cast(int, x),
                                  0x138, 0xf, 0xf, true));
}
__device__ __forceinline__ int dpp_shr1_zi(int x) {
  return __builtin_amdgcn_update_dpp(0, x, 0x138, 0xf, 0xf, true);
}
__device__ __forceinline__ float slog2(float x) {
  return x > 0.0f ? log2f(x) : -1.0e30f;
}
__device__ __forceinline__ float2 upk(unsigned u) {
  return __half22float2(__builtin_bit_cast(__half2, u));
}

__global__ __launch_bounds__(768, 1)
void k_fused(const float* __restrict__ logits,
             const int* __restrict__ targets,
             unsigned* __restrict__ pk,
             float* __restrict__ lbArr,
             float* __restrict__ out) {
  const int lane = threadIdx.x & 63;
  const int wv = threadIdx.x >> 6;              // 0..11
  const int p = blockIdx.x;
  const bool cons_blk = (p < BB);

  int q = -1;                                   // producer wave id
  if (cons_blk) { if (wv >= 2) q = p * 10 + (wv - 2); }
  else          q = 640 + (p - BB) * 12 + wv;
  const int slot = cons_blk ? (wv - 2) : wv;    // LDS scratch slot

  __shared__ float sx[12][KK];                  // 24 KB producer scratch
  __shared__ float sG[6][64];

  if (p == 0 && threadIdx.x == 0) out[0] = 0.0f;

  // ---------------- consumer setup (blocks < 64, waves 0/1) ------------
  float S0 = 0.0f, S1 = 0.0f, S2 = 0.0f, S3 = 0.0f;
  int ea = 0;
  float f1 = 1.0f, f2 = 1.0f;
  float mA = 0.0f, mB = 0.0f, mBb = 0.0f, mAn = 0.0f;
  const unsigned* gb = pk;
  if (cons_blk && wv < 2) {
    const int* tg = targets + p * LL;
    if (wv == 0) {
      gb = pk + (size_t)p * 512 * 128 + lane * 2;        // word = lane
      if (lane > 0 && 2 * lane <= LL - 1)
        mA = (tg[2 * lane] != tg[2 * lane - 1]) ? 1.0f : 0.0f;
      if (2 * lane + 1 <= LL - 1)
        mB = (tg[2 * lane + 1] != tg[2 * lane]) ? 1.0f : 0.0f;
      S0 = (lane == 0) ? 1.0f : 0.0f;           // virtual delta init
    } else {
      const int ii = 50 - lane;
      const int w = (ii >= 0) ? ii : 50;        // word 50 = zeros (pad)
      gb = pk + (size_t)p * 512 * 128 + w * 2;
      if (ii >= 0 && 2 * ii + 1 <= LL - 1)
        mBb = (tg[2 * ii + 1] != tg[2 * ii]) ? 1.0f : 0.0f;
      if (ii >= 0 && ii <= 48)
        mAn = (tg[2 * ii + 2] != tg[2 * ii + 1]) ? 1.0f : 0.0f;
      if (lane == 0) S0 = 1.0f;                 // state 200 (ii = 50)
      if (lane == 1) S3 = 1.0f;                 // state 199 (ii = 49)
    }
  }
  uint2 RA[8], RB[8], RC[8], RD[8];

#define RESC()                                                             \
  do {                                                                     \
    const float m_ = fmaxf(fmaxf(S0, S1), fmaxf(S2, S3));                  \
    int E_ = (int)((__float_as_uint(m_) >> 23) & 255) - 127;               \
    E_ = (m_ > 0.0f) ? E_ : 0;                                             \
    const float sc_ = __uint_as_float((unsigned)(127 - E_) << 23);         \
    S0 *= sc_; S1 *= sc_; S2 *= sc_; S3 *= sc_;                            \
    ea += E_;                                                              \
    int dE_ = dpp_shr1_zi(ea) - ea;                                        \
    dE_ = dE_ < -250 ? -250 : (dE_ > 250 ? 250 : dE_);                     \
    const int h_ = dE_ / 2;                                                \
    f1 = __uint_as_float((unsigned)(127 + h_) << 23);                      \
    f2 = __uint_as_float((unsigned)(127 + (dE_ - h_)) << 23);              \
  } while (0)

#define FSTEP(R)                                                           \
  do {                                                                     \
    const float A3 = dpp_shr1_z(S3) * f1 * f2;                             \
    const float n0 = S0 + A3;                                              \
    const float n1 = (S0 + S1 + mA * A3) * (R).x;                          \
    const float n2 = S1 + S2;                                              \
    const float n3 = (S2 + S3 + mB * S1) * (R).y;                          \
    S0 = n0; S1 = n1; S2 = n2; S3 = n3;                                    \
  } while (0)

#define BSTEP(R)                                                           \
  do {                                                                     \
    const float s2 = dpp_shr1_z((R).x);         /* label 2ii+2 ratio */    \
    const float H0 = dpp_shr1_z(S0) * f1 * f2;                             \
    const float H1 = dpp_shr1_z(S1) * f1 * f2;                             \
    const float u = (R).x * S1;                                            \
    const float v = (R).y * S3;                                            \
    const float n0 = S0 + u;                                               \
    const float n1 = u + fmaf(mBb, v, S2);                                 \
    const float n2 = S2 + v;                                               \
    const float n3 = v + fmaf(mAn, s2 * H1, H0);                           \
    S0 = n0; S1 = n1; S2 = n2; S3 = n3;                                    \
  } while (0)

#define FI(BUF, N)                                                         \
  do {                                                                     \
    _Pragma("unroll") for (int j = 0; j < 8; ++j)                          \
      BUF[j] = *reinterpret_cast<const uint2*>(                            \
          gb + (size_t)(fpb_ + 8 * (N) + j) * 128);                        \
    __builtin_amdgcn_sched_barrier(0);                                     \
  } while (0)
#define FC(BUF)                                                            \
  do {                                                                     \
    _Pragma("unroll") for (int j = 0; j < 8; ++j) {                        \
      const float2 re = upk(BUF[j].x);                                     \
      FSTEP(re);                                                           \
      const float2 ro = upk(BUF[j].y);                                     \
      FSTEP(ro);                                                           \
      if ((j & 3) == 3) RESC();                 /* every 8 steps */        \
    }                                                                      \
  } while (0)
#define FSEG(PB)                                                           \
  do { const int fpb_ = (PB);                                              \
    FI(RA, 0); FI(RB, 1); FI(RC, 2);                                       \
    FI(RD, 3); FC(RA);                                                     \
    FI(RA, 4); FC(RB);                                                     \
    FI(RB, 5); FC(RC);                                                     \
    FI(RC, 6); FC(RD);                                                     \
    FI(RD, 7); FC(RA);                                                     \
    FC(RB); FC(RC); FC(RD);                                                \
  } while (0)

#define BI(BUF, N)                                                         \
  do {                                                                     \
    _Pragma("unroll") for (int j = 0; j < 8; ++j)                          \
      BUF[j] = *reinterpret_cast<const uint2*>(                            \
          gb + (size_t)(bps_ - (8 * (N) + j)) * 128);                      \
    __builtin_amdgcn_sched_barrier(0);                                     \
  } while (0)
#define BC(BUF)                                                            \
  do {                                                                     \
    _Pragma("unroll") for (int j = 0; j < 8; ++j) {                        \
      const float2 ro = upk(BUF[j].y);                                     \
      BSTEP(ro);                                                           \
      const float2 re = upk(BUF[j].x);                                     \
      BSTEP(re);                                                           \
      if ((j & 3) == 3) RESC();                                            \
    }                                                                      \
  } while (0)
#define BSEG(PS)                                                           \
  do { const int bps_ = (PS);                                              \
    BI(RA, 0); BI(RB, 1); BI(RC, 2);                                       \
    BI(RD, 3); BC(RA);                                                     \
    BI(RA, 4); BC(RB);                                                     \
    BI(RB, 5); BC(RC);                                                     \
    BI(RC, 6); BC(RD);                                                     \
    BI(RD, 7); BC(RA);                                                     \
    BC(RB); BC(RC); BC(RD);                                                \
  } while (0)

  // ---------------- producer row processing ----------------------------
#define PROW(V0_, V1_, TC_, BR_, T_)                                       \
  do {                                                                     \
    float* sp_ = sx[slot];                                                 \
    float4* sp4_ = reinterpret_cast<float4*>(sp_);                         \
    sp4_[lane] = (V0_);                                                    \
    sp4_[lane + 64] = (V1_);                                               \
    float m_ = fmaxf(fmaxf(fmaxf((V0_).x, (V0_).y), fmaxf((V0_).z, (V0_).w)), \
                     fmaxf(fmaxf((V1_).x, (V1_).y), fmaxf((V1_).z, (V1_).w))); \
    _Pragma("unroll") for (int d_ = 1; d_ < 64; d_ <<= 1)                  \
      m_ = fmaxf(m_, __shfl_xor(m_, d_));                                  \
    float e_ = exp2f(((V0_).x - m_) * L2E) + exp2f(((V0_).y - m_) * L2E) + \
               exp2f(((V0_).z - m_) * L2E) + exp2f(((V0_).w - m_) * L2E) + \
               exp2f(((V1_).x - m_) * L2E) + exp2f(((V1_).y - m_) * L2E) + \
               exp2f(((V1_).z - m_) * L2E) + exp2f(((V1_).w - m_) * L2E);  \
    _Pragma("unroll") for (int d_ = 1; d_ < 64; d_ <<= 1)                  \
      e_ += __shfl_xor(e_, d_);                                            \
    const float xb_ = __builtin_bit_cast(float,                            \
        __builtin_amdgcn_readlane(__builtin_bit_cast(int, (V0_).x), 0));   \
    float ox_ = 0.0f, oy_ = 0.0f;                                          \
    if (lane >= 1 && lane <= 50) {                                         \
      ox_ = exp2f((sp_[(TC_).x] - xb_) * L2E);                             \
      oy_ = exp2f((sp_[(TC_).y] - xb_) * L2E);                             \
    }                                                                      \
    const int word_ = (lane == 0) ? 63 : (lane - 1);                       \
    const __half2 h_ = __floats2half2_rn(ox_, oy_);                        \
    const int row_ = (BR_)*TT + (T_);                                      \
    pk[(size_t)(row_ >> 1) * 128 + word_ * 2 + (row_ & 1)] =               \
        __builtin_bit_cast(unsigned, h_);                                  \
    if (lane == 0) lbArr[row_] = (xb_ - m_) * L2E + 9.0f - log2f(e_);      \
  } while (0)

#define PRODUCE(SS)                                                        \
  do {                                                                     \
    const int slo_ = (SS), shi_ = 7 - (SS);                                \
    float4 PV0[6], PV1[6]; int2 PTC[6]; int PBv[6], PTv[6];                \
    _Pragma("unroll") for (int j = 0; j < 6; ++j) {                        \
      const int r_ = q + j * NPRODW;                                       \
      if (j < 5 || r_ < RPS) {                                             \
        const int br_ = r_ >> 8, w8_ = r_ & 255;                           \
        const int t_ = (w8_ < 128) ? slo_ * 128 + w8_                      \
                                   : shi_ * 128 + (w8_ - 128);             \
        const float4* g_ = reinterpret_cast<const float4*>(                \
            logits + ((size_t)br_ * TT + t_) * KK);                        \
        PV0[j] = g_[lane];                                                 \
        PV1[j] = g_[lane + 64];                                            \
        int2 tc_; tc_.x = 0; tc_.y = 0;                                    \
        if (lane >= 1 && lane <= 50)                                       \
          tc_ = *reinterpret_cast<const int2*>(                            \
              targets + br_ * LL + 2 * (lane - 1));                        \
        PTC[j] = tc_; PBv[j] = br_; PTv[j] = t_;                           \
      }                                                                    \
    }                                                                      \
    __builtin_amdgcn_sched_barrier(0);                                     \
    _Pragma("unroll") for (int j = 0; j < 6; ++j) {                        \
      const int r_ = q + j * NPRODW;                                       \
      if (j < 5 || r_ < RPS) PROW(PV0[j], PV1[j], PTC[j], PBv[j], PTv[j]); \
    }                                                                      \
  } while (0)

#define SYNCF()                                                            \
  do {                                                                     \
    __builtin_amdgcn_fence(__ATOMIC_RELEASE, "agent");                     \
    cg::this_grid().sync();                                                \
    __builtin_amdgcn_fence(__ATOMIC_ACQUIRE, "agent");                     \
  } while (0)

  // ======================= pipeline ====================================
  if (q >= 0) PRODUCE(0);                       // segments {0, 7}
  SYNCF();
  for (int s = 1; s < 4; ++s) {
    if (q >= 0) PRODUCE(s);                     // segments {s, 7-s}
    else if (cons_blk && wv == 0) FSEG((s - 1) * 64);
    else if (cons_blk && wv == 1) BSEG((8 - s) * 64 + 63);
    SYNCF();
  }

  // ======================= tail + combine ==============================
  if (cons_blk) {
    float s4 = 0.0f;
    if (wv == 0) FSEG(192);                     // seg 3: rows 384..511
    else if (wv == 1) BSEG(319);                // seg 4: rows 639..512
    if (wv < 2) {
      const float4* lbv =
          reinterpret_cast<const float4*>(lbArr + (size_t)p * TT);
      const int lbb = (wv == 0) ? 0 : 128;
      const float4 a = lbv[lbb + lane];
      const float4 b2 = lbv[lbb + lane + 64];
      s4 = (a.x + a.y) + (a.z + a.w) + (b2.x + b2.y) + (b2.z + b2.w);
      #pragma unroll
      for (int d = 1; d < 64; d <<= 1) s4 += __shfl_xor(s4, d);
    }
    if (wv == 1) {
      sG[0][lane] = S0; sG[1][lane] = S1; sG[2][lane] = S2; sG[3][lane] = S3;
      sG[4][lane] = (float)ea;
      if (lane == 0) sG[5][0] = s4;
    }
    __syncthreads();
    if (wv == 0) {
      const int gj = (lane <= 50) ? (50 - lane) : 63;
      const float eb = sG[4][gj];
      const float eff = (float)ea;
      float w0 = slog2(S0) + eff + slog2(sG[0][gj]) + eb;
      float w1 = slog2(S1) + eff + slog2(sG[1][gj]) + eb;
      float w2 = slog2(S2) + eff + slog2(sG[2][gj]) + eb;
      float w3 = slog2(S3) + eff + slog2(sG[3][gj]) + eb;
      float wm = fmaxf(fmaxf(w0, w1), fmaxf(w2, w3));
      #pragma unroll
      for (int d = 1; d < 64; d <<= 1) wm = fmaxf(wm, __shfl_xor(wm, d));
      float ss = exp2f(w0 - wm) + exp2f(w1 - wm) +
                 exp2f(w2 - wm) + exp2f(w3 - wm);
      #pragma unroll
      for (int d = 1; d < 64; d <<= 1) ss += __shfl_xor(ss, d);
      if (lane == 0) {
        const float lbsum = s4 + sG[5][0];
        float loss = 0.0f;                      // zero_infinity
        if (wm > -1.0e29f) {
          const float logl2 = wm + log2f(ss) + lbsum - (float)(TT * 9);
          loss = -(logl2 * LN2) / (float)LL;
        }
        atomicAdd(out, loss * (1.0f / (float)BB));
      }
    }
  }
}

extern "C" void kernel_launch(void* const* d_in, const int* in_sizes, int n_in,
                              void* d_out, int out_size, void* d_ws, size_t ws_size,
                              hipStream_t stream) {
  const float* logits = (const float*)d_in[0];   // (64, 1024, 512) f32
  const int* targets = (const int*)d_in[1];      // (64, 100) i32
  float* out = (float*)d_out;                    // scalar f32

  unsigned* pk = (unsigned*)d_ws;                // 64*512*128 u32 (16 MB)
  float* lbArr = (float*)d_ws + (size_t)BB * 512 * 128;  // 64*1024 f32

  void* args[] = {(void*)&logits, (void*)&targets, (void*)&pk,
                  (void*)&lbArr, (void*)&out};
  hipLaunchCooperativeKernel((const void*)k_fused, dim3(256), dim3(768),
                             args, 0, stream);
}

// Round 17
// 67.523 us; speedup vs baseline: 7.2032x; 7.2032x over previous
//
#include <hip/hip_runtime.h>
#include <hip/hip_fp16.h>

// CTC loss (blank=0, mean reduction, zero_infinity) for
// B=64, T=1024, K=512, L=100  ->  S = 2L+1 = 201 extended states.
//
// Ratio formulation: factor prod_t p_blank(t) out of all alpha states.
//   even states: a' = sums;  odd states: a' = sums * r  (r = p_lab/p_blank)
//
// Round-17: wave-level TLP for the recursion. k_ctc = 16 blocks x 512
// threads (8 waves): waves 2k/2k+1 = fwd/bwd chains of batch 4*blk+k.
// Round-robin wave->SIMD assignment co-locates TWO independent chain
// waves per SIMD, so each chain's dependent-latency bubbles are filled
// by the other chain's issue (R12 lesson: single-wave interleave cannot
// do this; R15 lesson: prefetch depth is not the residual). Per-wave
// math is bit-identical to the verified R14/R15 kernel (fp16 pair-packed
// ratios, per-lane power-of-2 rescale every 8 steps with integer
// exponents + bit-built split factors, wave_shr:1 DPP cross-lane,
// log2-domain combine -> wave logsumexp, atomicAdd(out, loss/64)).
// R16 lesson (final): cross-block sync primitives (fences/coop barriers)
// are catastrophically expensive on this chip — the kernel boundary is
// the only cheap producer->consumer sync. Two dispatches, no more.

#define TT 1024
#define BB 64
#define KK 512
#define LL 100

static constexpr float L2E = 1.44269504088896340736f;
static constexpr float LN2 = 0.69314718055994530942f;

// lane i <- lane i-1, lane 0 <- 0  (DPP wave_shr:1, VALU pipe)
__device__ __forceinline__ float dpp_shr1_z(float x) {
  return __builtin_bit_cast(float,
      __builtin_amdgcn_update_dpp(0, __builtin_bit_cast(int, x),
                                  0x138, 0xf, 0xf, true));
}
__device__ __forceinline__ int dpp_shr1_zi(int x) {
  return __builtin_amdgcn_update_dpp(0, x, 0x138, 0xf, 0xf, true);
}
__device__ __forceinline__ float slog2(float x) {
  return x > 0.0f ? log2f(x) : -1.0e30f;
}
__device__ __forceinline__ float2 upk(unsigned u) {
  return __half22float2(__builtin_bit_cast(__half2, u));
}

__global__ __launch_bounds__(256) void k_probs(const float* __restrict__ logits,
                                               const int* __restrict__ targets,
                                               unsigned* __restrict__ pk,
                                               float* __restrict__ lbArr,
                                               float* __restrict__ out) {
  const int wid = threadIdx.x >> 6;
  const int lane = threadIdx.x & 63;
  const int row = (blockIdx.x << 2) + wid;      // row = b*T + t
  const int b = row >> 10;                      // T = 1024
  const float* x = logits + (size_t)row * KK;

  if (blockIdx.x == 0 && threadIdx.x == 0) out[0] = 0.0f;  // pre-k_ctc

  __shared__ float sx[4][KK];

  const float4 v0 = reinterpret_cast<const float4*>(x)[lane];
  const float4 v1 = reinterpret_cast<const float4*>(x)[lane + 64];
  float4* sp = reinterpret_cast<float4*>(sx[wid]);
  sp[lane] = v0;
  sp[lane + 64] = v1;

  float m = fmaxf(fmaxf(fmaxf(v0.x, v0.y), fmaxf(v0.z, v0.w)),
                  fmaxf(fmaxf(v1.x, v1.y), fmaxf(v1.z, v1.w)));
  #pragma unroll
  for (int d = 1; d < 64; d <<= 1) m = fmaxf(m, __shfl_xor(m, d));

  float e = exp2f((v0.x - m) * L2E) + exp2f((v0.y - m) * L2E) +
            exp2f((v0.z - m) * L2E) + exp2f((v0.w - m) * L2E) +
            exp2f((v1.x - m) * L2E) + exp2f((v1.y - m) * L2E) +
            exp2f((v1.z - m) * L2E) + exp2f((v1.w - m) * L2E);
  #pragma unroll
  for (int d = 1; d < 64; d <<= 1) e += __shfl_xor(e, d);

  __syncthreads();
  const float xb = sx[wid][0];                  // blank logit

  float ox = 0.0f, oy = 0.0f;
  if (lane >= 1 && lane <= 50) {
    const int2 c = *reinterpret_cast<const int2*>(
        targets + b * LL + (2 * lane - 2));
    ox = exp2f((sx[wid][c.x] - xb) * L2E);      // ratio p_lab / p_blank
    oy = exp2f((sx[wid][c.y] - xb) * L2E);
  }
  // word w holds labels 2w,2w+1; words 50..63 zero pads. pair element = t&1
  const int word = (lane == 0) ? 63 : (lane - 1);
  const __half2 h = __floats2half2_rn(ox, oy);
  pk[(size_t)(row >> 1) * 128 + word * 2 + (row & 1)] =
      __builtin_bit_cast(unsigned, h);

  // lb = log2(512 * p_blank) = (xb - m)*log2e + 9 - log2(sum exp)
  if (lane == 0) lbArr[row] = (xb - m) * L2E + 9.0f - log2f(e);
}

__global__ __launch_bounds__(512) void k_ctc(const unsigned* __restrict__ pk,
                                             const float* __restrict__ lbArr,
                                             const int* __restrict__ targets,
                                             float* __restrict__ out) {
  const int lane = threadIdx.x & 63;
  const int wv = threadIdx.x >> 6;              // 0..7
  const int pr = wv >> 1;                       // batch pair slot 0..3
  const int b = (blockIdx.x << 2) + pr;         // batch
  const int dir = wv & 1;                       // 0 = forward, 1 = backward
  const int i = lane;
  const int* tg = targets + b * LL;

  __shared__ float sG[4][6][64];                // per-batch exchange

  float S0 = 0.0f, S1 = 0.0f, S2 = 0.0f, S3 = 0.0f;
  int ea = 0;
  float f1 = 1.0f, f2 = 1.0f;

  // early-issue lb partial loads (independent of the recursion)
  const float4* lbv = reinterpret_cast<const float4*>(lbArr + (size_t)b * TT);
  const int lbbase = (dir == 0) ? 0 : 128;
  const float4 lb0 = lbv[lbbase + lane];
  const float4 lb1 = lbv[lbbase + lane + 64];

  // per-lane rescale: integer exponents, bit-constructed split factors
#define RESC()                                                             \
  do {                                                                     \
    const float m_ = fmaxf(fmaxf(S0, S1), fmaxf(S2, S3));                  \
    int E_ = (int)((__float_as_uint(m_) >> 23) & 255) - 127;               \
    E_ = (m_ > 0.0f) ? E_ : 0;                                             \
    const float sc_ = __uint_as_float((unsigned)(127 - E_) << 23);         \
    S0 *= sc_; S1 *= sc_; S2 *= sc_; S3 *= sc_;                            \
    ea += E_;                                                              \
    int dE_ = dpp_shr1_zi(ea) - ea;                                        \
    dE_ = dE_ < -250 ? -250 : (dE_ > 250 ? 250 : dE_);                     \
    const int h_ = dE_ / 2;                                                \
    f1 = __uint_as_float((unsigned)(127 + h_) << 23);                      \
    f2 = __uint_as_float((unsigned)(127 + (dE_ - h_)) << 23);              \
  } while (0)

  uint2 RA[8], RB[8], RC[8], RD[8];             // pair buffers (8/chunk)

  if (dir == 0) {
    // ---------- forward: rows 0..511, lane i = states 4i..4i+3 ----------
    const unsigned* gb = pk + (size_t)b * 512 * 128 + i * 2;  // word i
    float mA = 0.0f, mB = 0.0f;
    if (i > 0 && 2 * i <= LL - 1)
      mA = (tg[2 * i] != tg[2 * i - 1]) ? 1.0f : 0.0f;
    if (2 * i + 1 <= LL - 1)
      mB = (tg[2 * i + 1] != tg[2 * i]) ? 1.0f : 0.0f;
    S0 = (i == 0) ? 1.0f : 0.0f;                // virtual delta init

    // pair tp = CHN*8+j -> rows 2tp (.x) then 2tp+1 (.y)
#define FISSUE(BUF, CHN)                                                   \
    do {                                                                   \
      if ((CHN) < 32) {                                                    \
        _Pragma("unroll") for (int j = 0; j < 8; ++j)                      \
          BUF[j] = *reinterpret_cast<const uint2*>(                        \
              gb + (size_t)((CHN) * 8 + j) * 128);                         \
        __builtin_amdgcn_sched_barrier(0);                                 \
      }                                                                    \
    } while (0)
#define FSTEP(R)                                                           \
    do {                                                                   \
      const float A3 = dpp_shr1_z(S3) * f1 * f2;                           \
      const float n0 = S0 + A3;                                            \
      const float n1 = (S0 + S1 + mA * A3) * (R).x;                        \
      const float n2 = S1 + S2;                                            \
      const float n3 = (S2 + S3 + mB * S1) * (R).y;                        \
      S0 = n0; S1 = n1; S2 = n2; S3 = n3;                                  \
    } while (0)
#define FCOMPUTE(BUF)                                                      \
    do {                                                                   \
      _Pragma("unroll") for (int j = 0; j < 8; ++j) {                      \
        const float2 re = upk(BUF[j].x);                                   \
        FSTEP(re);                                                         \
        const float2 ro = upk(BUF[j].y);                                   \
        FSTEP(ro);                                                         \
        if ((j & 3) == 3) RESC();               /* every 8 steps */        \
      }                                                                    \
    } while (0)

    FISSUE(RA, 0); FISSUE(RB, 1); FISSUE(RC, 2);
    for (int c = 0; c < 32; c += 4) {
      FISSUE(RD, c + 3); FCOMPUTE(RA);
      FISSUE(RA, c + 4); FCOMPUTE(RB);
      FISSUE(RB, c + 5); FCOMPUTE(RC);
      FISSUE(RC, c + 6); FCOMPUTE(RD);
    }
#undef FISSUE
#undef FSTEP
#undef FCOMPUTE
  } else {
    // ------- backward: rows 1023..512, lane j = states of ii = 50-j -----
    const int ii = 50 - i;
    const int w = (ii >= 0) ? ii : 50;          // word 50 = zeros (pad)
    const unsigned* gb = pk + (size_t)b * 512 * 128 + w * 2;
    float mBb = 0.0f, mAn = 0.0f;
    if (ii >= 0 && 2 * ii + 1 <= LL - 1)
      mBb = (tg[2 * ii + 1] != tg[2 * ii]) ? 1.0f : 0.0f;
    if (ii >= 0 && ii <= 48)
      mAn = (tg[2 * ii + 2] != tg[2 * ii + 1]) ? 1.0f : 0.0f;
    if (i == 0) S0 = 1.0f;                      // state 200 (ii = 50)
    if (i == 1) S3 = 1.0f;                      // state 199 (ii = 49)

    // pair tp = 511-(CHN*8+j) -> rows 2tp+1 (.y) then 2tp (.x), descending
#define BISSUE(BUF, CHN)                                                   \
    do {                                                                   \
      if ((CHN) < 32) {                                                    \
        _Pragma("unroll") for (int j = 0; j < 8; ++j)                      \
          BUF[j] = *reinterpret_cast<const uint2*>(                        \
              gb + (size_t)(511 - ((CHN) * 8 + j)) * 128);                 \
        __builtin_amdgcn_sched_barrier(0);                                 \
      }                                                                    \
    } while (0)
#define BSTEP(R)                                                           \
    do {                                                                   \
      const float s2 = dpp_shr1_z((R).x);       /* label 2ii+2 ratio */    \
      const float H0 = dpp_shr1_z(S0) * f1 * f2;                           \
      const float H1 = dpp_shr1_z(S1) * f1 * f2;                           \
      const float u = (R).x * S1;                                          \
      const float v = (R).y * S3;                                          \
      const float n0 = S0 + u;                                             \
      const float n1 = u + fmaf(mBb, v, S2);                               \
      const float n2 = S2 + v;                                             \
      const float n3 = v + fmaf(mAn, s2 * H1, H0);                         \
      S0 = n0; S1 = n1; S2 = n2; S3 = n3;                                  \
    } while (0)
#define BCOMPUTE(BUF)                                                      \
    do {                                                                   \
      _Pragma("unroll") for (int j = 0; j < 8; ++j) {                      \
        const float2 ro = upk(BUF[j].y);                                   \
        BSTEP(ro);                                                         \
        const float2 re = upk(BUF[j].x);                                   \
        BSTEP(re);                                                         \
        if ((j & 3) == 3) RESC();               /* every 8 steps */        \
      }                                                                    \
    } while (0)

    BISSUE(RA, 0); BISSUE(RB, 1); BISSUE(RC, 2);
    for (int c = 0; c < 32; c += 4) {
      BISSUE(RD, c + 3); BCOMPUTE(RA);
      BISSUE(RA, c + 4); BCOMPUTE(RB);
      BISSUE(RB, c + 5); BCOMPUTE(RC);
      BISSUE(RC, c + 6); BCOMPUTE(RD);
    }
#undef BISSUE
#undef BSTEP
#undef BCOMPUTE
  }
#undef RESC

  // lb partial reduce (loads were issued before the main loop)
  float s4 = (lb0.x + lb0.y) + (lb0.z + lb0.w) +
             (lb1.x + lb1.y) + (lb1.z + lb1.w);
  #pragma unroll
  for (int d = 1; d < 64; d <<= 1) s4 += __shfl_xor(s4, d);

  if (dir == 1) {
    sG[pr][0][lane] = S0; sG[pr][1][lane] = S1;
    sG[pr][2][lane] = S2; sG[pr][3][lane] = S3;
    sG[pr][4][lane] = (float)ea;
    if (lane == 0) sG[pr][5][0] = s4;
  }

  __syncthreads();                              // backward waves publish sG

  if (dir == 0) {
    const int gj = (i <= 50) ? (50 - i) : 63;   // bwd lane w/ states 4i..
    const float eb = sG[pr][4][gj];
    const float eff = (float)ea;
    float w0 = slog2(S0) + eff + slog2(sG[pr][0][gj]) + eb;
    float w1 = slog2(S1) + eff + slog2(sG[pr][1][gj]) + eb;
    float w2 = slog2(S2) + eff + slog2(sG[pr][2][gj]) + eb;
    float w3 = slog2(S3) + eff + slog2(sG[pr][3][gj]) + eb;
    float wm = fmaxf(fmaxf(w0, w1), fmaxf(w2, w3));
    #pragma unroll
    for (int d = 1; d < 64; d <<= 1) wm = fmaxf(wm, __shfl_xor(wm, d));
    float ss = exp2f(w0 - wm) + exp2f(w1 - wm) +
               exp2f(w2 - wm) + exp2f(w3 - wm);
    #pragma unroll
    for (int d = 1; d < 64; d <<= 1) ss += __shfl_xor(ss, d);

    if (i == 0) {
      const float lbsum = s4 + sG[pr][5][0];    // fwd + bwd halves
      float loss = 0.0f;                        // zero_infinity
      if (wm > -1.0e29f) {
        const float logl2 = wm + log2f(ss) + lbsum - (float)(TT * 9);
        loss = -(logl2 * LN2) / (float)LL;
      }
      atomicAdd(out, loss * (1.0f / (float)BB));
    }
  }
}

extern "C" void kernel_launch(void* const* d_in, const int* in_sizes, int n_in,
                              void* d_out, int out_size, void* d_ws, size_t ws_size,
                              hipStream_t stream) {
  const float* logits = (const float*)d_in[0];   // (64, 1024, 512) f32
  const int* targets = (const int*)d_in[1];      // (64, 100) i32
  float* out = (float*)d_out;                    // scalar f32

  unsigned* pk = (unsigned*)d_ws;                // 64*512*128 u32 (16 MB)
  float* lbArr = (float*)d_ws + (size_t)BB * 512 * 128;  // 64*1024 f32

  hipLaunchKernelGGL(k_probs, dim3(BB * TT / 4), dim3(256), 0, stream,
                     logits, targets, pk, lbArr, out);
  hipLaunchKernelGGL(k_ctc, dim3(BB / 4), dim3(512), 0, stream,
                     pk, lbArr, targets, out);
}

// Round 18
// 47.853 us; speedup vs baseline: 10.1640x; 1.4110x over previous
//
#include <hip/hip_runtime.h>
#include <hip/hip_fp16.h>

// CTC loss (blank=0, mean reduction, zero_infinity) for
// B=64, T=1024, K=512, L=100  ->  S = 2L+1 = 201 extended states.
//
// Ratio formulation: factor prod_t p_blank(t) out of all alpha states.
//   even states: a' = sums;  odd states: a' = sums * r  (r = p_lab/p_blank)
//
// Round-18: partial producer/consumer overlap using ONLY kernel-boundary
// sync (R10/R16 lesson: fences/coop barriers are catastrophic; R17
// lesson: chains are issue-bound — don't co-locate on a SIMD).
//   K1 k_probs_edge: produce rows [0,320) u [704,1024) for all batches
//     (the rows the chains consume first). Zeroes out[].
//   K2 k_mid: blocks 0..63 = chain blocks (verified R15 2-wave fwd/bwd)
//     running the FIRST 320 steps per direction — reads only K1 rows, so
//     no intra-kernel dependency; blocks 64..6207 produce the middle
//     rows [320,704) on the remaining CUs CONCURRENTLY. Chains save
//     state (4 floats + exponent per lane) to scratch.
//   K3 k_tail: restore state, run last 192 steps per direction, then the
//     verified log2-domain combine -> wave logsumexp -> atomicAdd.
// Recursion math is byte-identical to the absmax-0.0 R15 kernel: fp16
// pair-packed ratios pk[b][t/2][word][2], per-lane power-of-2 rescale
// every 8 steps (integer exponents, bit-built split factors f1*f2),
// wave_shr:1 DPP cross-lane only.

#define TT 1024
#define BB 64
#define KK 512
#define LL 100
#define DLT 320               // steps done in K2 (20 chunks of 16 steps)

static constexpr float L2E = 1.44269504088896340736f;
static constexpr float LN2 = 0.69314718055994530942f;

// lane i <- lane i-1, lane 0 <- 0  (DPP wave_shr:1, VALU pipe)
__device__ __forceinline__ float dpp_shr1_z(float x) {
  return __builtin_bit_cast(float,
      __builtin_amdgcn_update_dpp(0, __builtin_bit_cast(int, x),
                                  0x138, 0xf, 0xf, true));
}
__device__ __forceinline__ int dpp_shr1_zi(int x) {
  return __builtin_amdgcn_update_dpp(0, x, 0x138, 0xf, 0xf, true);
}
__device__ __forceinline__ float slog2(float x) {
  return x > 0.0f ? log2f(x) : -1.0e30f;
}
__device__ __forceinline__ float2 upk(unsigned u) {
  return __half22float2(__builtin_bit_cast(__half2, u));
}

// per-lane rescale: integer exponents, bit-constructed split factors
__device__ __forceinline__ void resc(float& S0, float& S1, float& S2,
                                     float& S3, int& ea, float& f1,
                                     float& f2) {
  const float m = fmaxf(fmaxf(S0, S1), fmaxf(S2, S3));
  int E = (int)((__float_as_uint(m) >> 23) & 255) - 127;
  E = (m > 0.0f) ? E : 0;
  const float sc = __uint_as_float((unsigned)(127 - E) << 23);
  S0 *= sc; S1 *= sc; S2 *= sc; S3 *= sc;
  ea += E;
  int dE = dpp_shr1_zi(ea) - ea;
  dE = dE < -250 ? -250 : (dE > 250 ? 250 : dE);
  const int h = dE / 2;
  f1 = __uint_as_float((unsigned)(127 + h) << 23);
  f2 = __uint_as_float((unsigned)(127 + (dE - h)) << 23);
}
__device__ __forceinline__ void refresh_f(int ea, float& f1, float& f2) {
  int dE = dpp_shr1_zi(ea) - ea;
  dE = dE < -250 ? -250 : (dE > 250 ? 250 : dE);
  const int h = dE / 2;
  f1 = __uint_as_float((unsigned)(127 + h) << 23);
  f2 = __uint_as_float((unsigned)(127 + (dE - h)) << 23);
}

__device__ __forceinline__ void fstep(float2 r, float mA, float mB,
                                      float& S0, float& S1, float& S2,
                                      float& S3, float f1, float f2) {
  const float A3 = dpp_shr1_z(S3) * f1 * f2;
  const float n0 = S0 + A3;
  const float n1 = (S0 + S1 + mA * A3) * r.x;
  const float n2 = S1 + S2;
  const float n3 = (S2 + S3 + mB * S1) * r.y;
  S0 = n0; S1 = n1; S2 = n2; S3 = n3;
}
__device__ __forceinline__ void bstep(float2 r, float mBb, float mAn,
                                      float& S0, float& S1, float& S2,
                                      float& S3, float f1, float f2) {
  const float s2 = dpp_shr1_z(r.x);             // label 2ii+2 ratio
  const float H0 = dpp_shr1_z(S0) * f1 * f2;
  const float H1 = dpp_shr1_z(S1) * f1 * f2;
  const float u = r.x * S1;
  const float v = r.y * S3;
  const float n0 = S0 + u;
  const float n1 = u + fmaf(mBb, v, S2);
  const float n2 = S2 + v;
  const float n3 = v + fmaf(mAn, s2 * H1, H0);
  S0 = n0; S1 = n1; S2 = n2; S3 = n3;
}

// chunk segment runners: CB = first chunk, NC = chunk count (16 steps ea)
template <int CB, int NC>
__device__ __forceinline__ void run_fwd(const unsigned* __restrict__ gb,
                                        float mA, float mB, float& S0,
                                        float& S1, float& S2, float& S3,
                                        int& ea, float& f1, float& f2) {
  uint2 RA[8], RB[8], RC[8], RD[8];
#define ISSUE(BUF, CHN)                                                    \
  do {                                                                     \
    if ((CHN) < NC) {                                                      \
      _Pragma("unroll") for (int j = 0; j < 8; ++j)                        \
        BUF[j] = *reinterpret_cast<const uint2*>(                          \
            gb + (size_t)((CB + (CHN)) * 8 + j) * 128);                    \
      __builtin_amdgcn_sched_barrier(0);                                   \
    }                                                                      \
  } while (0)
#define COMP(BUF)                                                          \
  do {                                                                     \
    _Pragma("unroll") for (int j = 0; j < 8; ++j) {                        \
      fstep(upk(BUF[j].x), mA, mB, S0, S1, S2, S3, f1, f2);                \
      fstep(upk(BUF[j].y), mA, mB, S0, S1, S2, S3, f1, f2);                \
      if ((j & 3) == 3) resc(S0, S1, S2, S3, ea, f1, f2);                  \
    }                                                                      \
  } while (0)
  ISSUE(RA, 0); ISSUE(RB, 1); ISSUE(RC, 2);
  for (int c = 0; c < NC; c += 4) {
    ISSUE(RD, c + 3); COMP(RA);
    ISSUE(RA, c + 4); COMP(RB);
    ISSUE(RB, c + 5); COMP(RC);
    ISSUE(RC, c + 6); COMP(RD);
  }
#undef ISSUE
#undef COMP
}

template <int CB, int NC>
__device__ __forceinline__ void run_bwd(const unsigned* __restrict__ gb,
                                        float mBb, float mAn, float& S0,
                                        float& S1, float& S2, float& S3,
                                        int& ea, float& f1, float& f2) {
  uint2 RA[8], RB[8], RC[8], RD[8];
#define ISSUE(BUF, CHN)                                                    \
  do {                                                                     \
    if ((CHN) < NC) {                                                      \
      _Pragma("unroll") for (int j = 0; j < 8; ++j)                        \
        BUF[j] = *reinterpret_cast<const uint2*>(                          \
            gb + (size_t)(511 - ((CB + (CHN)) * 8 + j)) * 128);            \
      __builtin_amdgcn_sched_barrier(0);                                   \
    }                                                                      \
  } while (0)
#define COMP(BUF)                                                          \
  do {                                                                     \
    _Pragma("unroll") for (int j = 0; j < 8; ++j) {                        \
      bstep(upk(BUF[j].y), mBb, mAn, S0, S1, S2, S3, f1, f2);              \
      bstep(upk(BUF[j].x), mBb, mAn, S0, S1, S2, S3, f1, f2);              \
      if ((j & 3) == 3) resc(S0, S1, S2, S3, ea, f1, f2);                  \
    }                                                                      \
  } while (0)
  ISSUE(RA, 0); ISSUE(RB, 1); ISSUE(RC, 2);
  for (int c = 0; c < NC; c += 4) {
    ISSUE(RD, c + 3); COMP(RA);
    ISSUE(RA, c + 4); COMP(RB);
    ISSUE(RB, c + 5); COMP(RC);
    ISSUE(RC, c + 6); COMP(RD);
  }
#undef ISSUE
#undef COMP
}

// one softmax row: 100 target ratios -> fp16x2 pair-packed pk + lb
__device__ __forceinline__ void prob_row(const float* __restrict__ logits,
                                         const int* __restrict__ targets,
                                         unsigned* __restrict__ pk,
                                         float* __restrict__ lbArr,
                                         int b, int t, int lane, float* sp) {
  const int row = (b << 10) + t;
  const float* x = logits + (size_t)row * KK;
  const float4 v0 = reinterpret_cast<const float4*>(x)[lane];
  const float4 v1 = reinterpret_cast<const float4*>(x)[lane + 64];
  float4* sp4 = reinterpret_cast<float4*>(sp);
  sp4[lane] = v0;
  sp4[lane + 64] = v1;

  float m = fmaxf(fmaxf(fmaxf(v0.x, v0.y), fmaxf(v0.z, v0.w)),
                  fmaxf(fmaxf(v1.x, v1.y), fmaxf(v1.z, v1.w)));
  #pragma unroll
  for (int d = 1; d < 64; d <<= 1) m = fmaxf(m, __shfl_xor(m, d));

  float e = exp2f((v0.x - m) * L2E) + exp2f((v0.y - m) * L2E) +
            exp2f((v0.z - m) * L2E) + exp2f((v0.w - m) * L2E) +
            exp2f((v1.x - m) * L2E) + exp2f((v1.y - m) * L2E) +
            exp2f((v1.z - m) * L2E) + exp2f((v1.w - m) * L2E);
  #pragma unroll
  for (int d = 1; d < 64; d <<= 1) e += __shfl_xor(e, d);

  __syncthreads();
  const float xb = sp[0];                       // blank logit

  float ox = 0.0f, oy = 0.0f;
  if (lane >= 1 && lane <= 50) {
    const int2 c = *reinterpret_cast<const int2*>(
        targets + b * LL + (2 * lane - 2));
    ox = exp2f((sp[c.x] - xb) * L2E);           // ratio p_lab / p_blank
    oy = exp2f((sp[c.y] - xb) * L2E);
  }
  const int word = (lane == 0) ? 63 : (lane - 1);
  const __half2 h = __floats2half2_rn(ox, oy);
  pk[(size_t)(row >> 1) * 128 + word * 2 + (row & 1)] =
      __builtin_bit_cast(unsigned, h);
  if (lane == 0) lbArr[row] = (xb - m) * L2E + 9.0f - log2f(e);
}

// K1: edge rows [0,320) u [704,1024), all batches. 640 rows/batch.
__global__ __launch_bounds__(256) void k_probs_edge(
    const float* __restrict__ logits, const int* __restrict__ targets,
    unsigned* __restrict__ pk, float* __restrict__ lbArr,
    float* __restrict__ out) {
  if (blockIdx.x == 0 && threadIdx.x == 0) out[0] = 0.0f;
  const int wid = threadIdx.x >> 6;
  const int lane = threadIdx.x & 63;
  __shared__ float sx[4][KK];
  const int e = (blockIdx.x << 2) + wid;        // 0..40959
  const int b = e / 640;
  const int w = e - b * 640;
  const int t = (w < DLT) ? w : (TT - 640) + w; // [0,320) u [704,1024)
  prob_row(logits, targets, pk, lbArr, b, t, lane, sx[wid]);
}

// K2: blocks 0..63 = chain prefix (320 steps/dir, reads K1 rows only);
//     blocks 64.. = produce middle rows [320,704).
__global__ __launch_bounds__(256) void k_mid(
    const float* __restrict__ logits, const int* __restrict__ targets,
    unsigned* __restrict__ pk, float* __restrict__ lbArr,
    float* __restrict__ st) {
  const int lane = threadIdx.x & 63;
  const int wv = threadIdx.x >> 6;
  __shared__ float sx[4][KK];

  if (blockIdx.x >= BB) {
    const int m = ((blockIdx.x - BB) << 2) + wv; // 0..24575
    const int b = m / 384;
    const int w = m - b * 384;
    prob_row(logits, targets, pk, lbArr, b, DLT + w, lane, sx[wv]);
    return;
  }

  if (wv >= 2) return;                          // chain blocks: 2 waves
  const int b = blockIdx.x;
  const int dir = wv;                           // 0 = fwd, 1 = bwd
  const int* tg = targets + b * LL;

  float S0 = 0.0f, S1 = 0.0f, S2 = 0.0f, S3 = 0.0f;
  int ea = 0;
  float f1 = 1.0f, f2 = 1.0f;

  if (dir == 0) {
    const unsigned* gb = pk + (size_t)b * 512 * 128 + lane * 2;
    float mA = 0.0f, mB = 0.0f;
    if (lane > 0 && 2 * lane <= LL - 1)
      mA = (tg[2 * lane] != tg[2 * lane - 1]) ? 1.0f : 0.0f;
    if (2 * lane + 1 <= LL - 1)
      mB = (tg[2 * lane + 1] != tg[2 * lane]) ? 1.0f : 0.0f;
    S0 = (lane == 0) ? 1.0f : 0.0f;             // virtual delta init
    run_fwd<0, 20>(gb, mA, mB, S0, S1, S2, S3, ea, f1, f2);
  } else {
    const int ii = 50 - lane;
    const int w = (ii >= 0) ? ii : 50;          // word 50 = zeros (pad)
    const unsigned* gb = pk + (size_t)b * 512 * 128 + w * 2;
    float mBb = 0.0f, mAn = 0.0f;
    if (ii >= 0 && 2 * ii + 1 <= LL - 1)
      mBb = (tg[2 * ii + 1] != tg[2 * ii]) ? 1.0f : 0.0f;
    if (ii >= 0 && ii <= 48)
      mAn = (tg[2 * ii + 2] != tg[2 * ii + 1]) ? 1.0f : 0.0f;
    if (lane == 0) S0 = 1.0f;                   // state 200 (ii = 50)
    if (lane == 1) S3 = 1.0f;                   // state 199 (ii = 49)
    run_bwd<0, 20>(gb, mBb, mAn, S0, S1, S2, S3, ea, f1, f2);
  }

  float* stp = st + (size_t)(b * 2 + dir) * 5 * 64;
  stp[0 * 64 + lane] = S0;
  stp[1 * 64 + lane] = S1;
  stp[2 * 64 + lane] = S2;
  stp[3 * 64 + lane] = S3;
  stp[4 * 64 + lane] = __int_as_float(ea);
}

// K3: restore, run last 192 steps/dir, combine (verified R15 epilogue).
__global__ __launch_bounds__(128) void k_tail(
    const unsigned* __restrict__ pk, const float* __restrict__ lbArr,
    const int* __restrict__ targets, const float* __restrict__ st,
    float* __restrict__ out) {
  const int lane = threadIdx.x & 63;
  const int wv = threadIdx.x >> 6;              // 0 = fwd, 1 = bwd
  const int b = blockIdx.x;
  const int dir = wv;
  const int* tg = targets + b * LL;

  __shared__ float sG[6][64];

  // early-issue lb partial loads (independent of the recursion)
  const float4* lbv = reinterpret_cast<const float4*>(lbArr + (size_t)b * TT);
  const int lbbase = (dir == 0) ? 0 : 128;
  const float4 lb0 = lbv[lbbase + lane];
  const float4 lb1 = lbv[lbbase + lane + 64];

  // restore state from K2
  const float* stp = st + (size_t)(b * 2 + dir) * 5 * 64;
  float S0 = stp[0 * 64 + lane];
  float S1 = stp[1 * 64 + lane];
  float S2 = stp[2 * 64 + lane];
  float S3 = stp[3 * 64 + lane];
  int ea = __float_as_int(stp[4 * 64 + lane]);
  float f1, f2;
  refresh_f(ea, f1, f2);                        // same values K2 ended with

  if (dir == 0) {
    const unsigned* gb = pk + (size_t)b * 512 * 128 + lane * 2;
    float mA = 0.0f, mB = 0.0f;
    if (lane > 0 && 2 * lane <= LL - 1)
      mA = (tg[2 * lane] != tg[2 * lane - 1]) ? 1.0f : 0.0f;
    if (2 * lane + 1 <= LL - 1)
      mB = (tg[2 * lane + 1] != tg[2 * lane]) ? 1.0f : 0.0f;
    run_fwd<20, 12>(gb, mA, mB, S0, S1, S2, S3, ea, f1, f2);
  } else {
    const int ii = 50 - lane;
    const int w = (ii >= 0) ? ii : 50;
    const unsigned* gb = pk + (size_t)b * 512 * 128 + w * 2;
    float mBb = 0.0f, mAn = 0.0f;
    if (ii >= 0 && 2 * ii + 1 <= LL - 1)
      mBb = (tg[2 * ii + 1] != tg[2 * ii]) ? 1.0f : 0.0f;
    if (ii >= 0 && ii <= 48)
      mAn = (tg[2 * ii + 2] != tg[2 * ii + 1]) ? 1.0f : 0.0f;
    run_bwd<20, 12>(gb, mBb, mAn, S0, S1, S2, S3, ea, f1, f2);
  }

  // lb partial reduce
  float s4 = (lb0.x + lb0.y) + (lb0.z + lb0.w) +
             (lb1.x + lb1.y) + (lb1.z + lb1.w);
  #pragma unroll
  for (int d = 1; d < 64; d <<= 1) s4 += __shfl_xor(s4, d);

  if (dir == 1) {
    sG[0][lane] = S0; sG[1][lane] = S1; sG[2][lane] = S2; sG[3][lane] = S3;
    sG[4][lane] = (float)ea;
    if (lane == 0) sG[5][0] = s4;
  }
  __syncthreads();                              // backward publishes sG

  if (dir == 0) {
    const int gj = (lane <= 50) ? (50 - lane) : 63;
    const float eb = sG[4][gj];
    const float eff = (float)ea;
    float w0 = slog2(S0) + eff + slog2(sG[0][gj]) + eb;
    float w1 = slog2(S1) + eff + slog2(sG[1][gj]) + eb;
    float w2 = slog2(S2) + eff + slog2(sG[2][gj]) + eb;
    float w3 = slog2(S3) + eff + slog2(sG[3][gj]) + eb;
    float wm = fmaxf(fmaxf(w0, w1), fmaxf(w2, w3));
    #pragma unroll
    for (int d = 1; d < 64; d <<= 1) wm = fmaxf(wm, __shfl_xor(wm, d));
    float ss = exp2f(w0 - wm) + exp2f(w1 - wm) +
               exp2f(w2 - wm) + exp2f(w3 - wm);
    #pragma unroll
    for (int d = 1; d < 64; d <<= 1) ss += __shfl_xor(ss, d);

    if (lane == 0) {
      const float lbsum = s4 + sG[5][0];        // fwd + bwd halves
      float loss = 0.0f;                        // zero_infinity
      if (wm > -1.0e29f) {
        const float logl2 = wm + log2f(ss) + lbsum - (float)(TT * 9);
        loss = -(logl2 * LN2) / (float)LL;
      }
      atomicAdd(out, loss * (1.0f / (float)BB));
    }
  }
}

extern "C" void kernel_launch(void* const* d_in, const int* in_sizes, int n_in,
                              void* d_out, int out_size, void* d_ws, size_t ws_size,
                              hipStream_t stream) {
  const float* logits = (const float*)d_in[0];   // (64, 1024, 512) f32
  const int* targets = (const int*)d_in[1];      // (64, 100) i32
  float* out = (float*)d_out;                    // scalar f32

  unsigned* pk = (unsigned*)d_ws;                // 64*512*128 u32 (16 MB)
  float* lbArr = (float*)d_ws + (size_t)BB * 512 * 128;  // 64*1024 f32
  float* st = lbArr + (size_t)BB * TT;           // 64*2*5*64 f32

  hipLaunchKernelGGL(k_probs_edge, dim3(BB * 640 / 4), dim3(256), 0, stream,
                     logits, targets, pk, lbArr, out);
  hipLaunchKernelGGL(k_mid, dim3(BB + BB * 384 / 4), dim3(256), 0, stream,
                     logits, targets, pk, lbArr, st);
  hipLaunchKernelGGL(k_tail, dim3(BB), dim3(128), 0, stream,
                     pk, lbArr, targets, st, out);
}